// Round 7
// baseline (258.229 us; speedup 1.0000x reference)
//
#include <hip/hip_runtime.h>
#include <hip/hip_bf16.h>

// Problem constants
constexpr int   DIMC  = 512;
constexpr int   PARTC = 6;
constexpr int   NTOK  = 162;
constexpr int   NTOT  = 1024 * NTOK;          // 165888 token rows
constexpr float SCALING = 22.62741699796952f; // sqrt(512)
constexpr float LNEPS   = 1e-5f;

typedef __attribute__((ext_vector_type(8))) short bf16x8;
typedef __attribute__((ext_vector_type(4))) float f32x4;

// ---------------------------------------------------------------------------
// K0: transpose f32 [R][C] -> bf16 [C][R]
// ---------------------------------------------------------------------------
__global__ __launch_bounds__(256) void transpose_f32_bf16(
    const float* __restrict__ in, __hip_bfloat16* __restrict__ outp, int R, int C)
{
  __shared__ float tile[32][33];
  const int tx = threadIdx.x, ty = threadIdx.y;
  const int bx = blockIdx.x, by = blockIdx.y;
  const int c = bx * 32 + tx;
#pragma unroll
  for (int i = 0; i < 32; i += 8) {
    int r = by * 32 + ty + i;
    tile[ty + i][tx] = in[(size_t)r * C + c];
  }
  __syncthreads();
#pragma unroll
  for (int i = 0; i < 32; i += 8) {
    outp[(size_t)(bx * 32 + ty + i) * R + by * 32 + tx] =
        __float2bfloat16(tile[tx][ty + i]);
  }
}

// ---------------------------------------------------------------------------
// K1a: logits + f32->bf16 conversion of x.  Pure streaming, no LDS/barriers.
// Wave-per-token grid-stride: 8192 independent waves, ~16 waves/CU.
//   lane covers dims [8l, 8l+8): 2 x dwordx4 load, int4 bf16 store,
//   6 f32 dots + butterfly reduce; lane 0 stores 6 logits.
// ---------------------------------------------------------------------------
__global__ __launch_bounds__(256) void logits_conv_k(
    const float* __restrict__ x,          // [165888][512]
    const float* __restrict__ pt,         // [6][512]
    __hip_bfloat16* __restrict__ XB,      // [165888][512] bf16 out
    float* __restrict__ lg)               // [1024][6][162] f32 out
{
  const int lane = threadIdx.x & 63;
  const int wid = (blockIdx.x << 2) + (threadIdx.x >> 6);  // 0..8191

  float4 pA[PARTC], pB[PARTC];
#pragma unroll
  for (int p = 0; p < PARTC; ++p) {
    pA[p] = *(const float4*)(pt + p * DIMC + 8 * lane);
    pB[p] = *(const float4*)(pt + p * DIMC + 8 * lane + 4);
  }

  for (int t = wid; t < NTOT; t += 8192) {
    const float* xr = x + (size_t)t * DIMC;
    float4 xa = *(const float4*)(xr + 8 * lane);
    float4 xc = *(const float4*)(xr + 8 * lane + 4);

    // bf16 pack + store (coalesced 16B/lane)
    union { unsigned short u[8]; int4 v; } pk;
#pragma unroll
    for (int j = 0; j < 4; ++j) {
      __hip_bfloat16 h0 = __float2bfloat16(((const float*)&xa)[j]);
      __hip_bfloat16 h1 = __float2bfloat16(((const float*)&xc)[j]);
      pk.u[j]     = *(const unsigned short*)&h0;
      pk.u[4 + j] = *(const unsigned short*)&h1;
    }
    *(int4*)((unsigned short*)XB + (size_t)t * DIMC + 8 * lane) = pk.v;

    float acc[PARTC];
#pragma unroll
    for (int p = 0; p < PARTC; ++p) {
      acc[p] = xa.x * pA[p].x + xa.y * pA[p].y + xa.z * pA[p].z + xa.w * pA[p].w
             + xc.x * pB[p].x + xc.y * pB[p].y + xc.z * pB[p].z + xc.w * pB[p].w;
    }
#pragma unroll
    for (int off = 32; off > 0; off >>= 1) {
#pragma unroll
      for (int p = 0; p < PARTC; ++p) acc[p] += __shfl_xor(acc[p], off);
    }
    if (lane == 0) {
      const int b = t / NTOK;
      const int n = t - b * NTOK;
      float* lr = lg + (size_t)b * (PARTC * NTOK) + n;
#pragma unroll
      for (int p = 0; p < PARTC; ++p) lr[p * NTOK] = acc[p];
    }
  }
}

// ---------------------------------------------------------------------------
// K1b: softmax + PV (bf16 x) + /sqrt(512) + LayerNorm.  Block = one b.
// ~8KB LDS, 4 barriers; thread owns dims (2t, 2t+1).
// ---------------------------------------------------------------------------
__global__ __launch_bounds__(256) void pv_ln_k(
    const __hip_bfloat16* __restrict__ XB,  // [165888][512] bf16
    const float* __restrict__ lg,           // [1024][6][162]
    const float* __restrict__ g,
    const float* __restrict__ bta,
    __hip_bfloat16* __restrict__ outp)      // [1024*6][512] bf16
{
  const int b = blockIdx.x;
  const int tid = threadIdx.x;
  const int w = tid >> 6;
  const int lane = tid & 63;

  __shared__ float s_logit[PARTC * NTOK];        // flat [p][162]
  __shared__ __align__(16) float s_w[PARTC][164];
  __shared__ float s_l[PARTC];
  __shared__ float s_red[4][2 * PARTC];

  // load logits (972 contiguous f32)
  for (int i = tid; i < PARTC * NTOK; i += 256)
    s_logit[i] = lg[(size_t)b * (PARTC * NTOK) + i];
  __syncthreads();

  // softmax: 32-lane group per part (shfl widths <=16 stay in-group)
  if (tid < PARTC * 32) {
    const int grp = tid >> 5, gl = tid & 31;
    float m = -1e30f;
    for (int i = gl; i < NTOK; i += 32) m = fmaxf(m, s_logit[grp * NTOK + i]);
#pragma unroll
    for (int off = 16; off > 0; off >>= 1) m = fmaxf(m, __shfl_xor(m, off));
    float s = 0.f;
    for (int i = gl; i < 164; i += 32) {
      float wv = (i < NTOK) ? __expf(s_logit[grp * NTOK + i] - m) : 0.f;
      s_w[grp][i] = wv;
      s += wv;
    }
#pragma unroll
    for (int off = 16; off > 0; off >>= 1) s += __shfl_xor(s, off);
    if (gl == 0) s_l[grp] = s;
  }
  __syncthreads();

  // PV: thread owns dims (2t, 2t+1); u32 loads unpack 2 bf16
  float u0[PARTC], u1[PARTC];
#pragma unroll
  for (int p = 0; p < PARTC; ++p) { u0[p] = 0.f; u1[p] = 0.f; }

  const unsigned int* xc =
      (const unsigned int*)(XB + (size_t)b * NTOK * DIMC) + tid;
  for (int n0 = 0; n0 < 160; n0 += 4) {
    f32x4 wv[PARTC];
#pragma unroll
    for (int p = 0; p < PARTC; ++p) wv[p] = *(const f32x4*)&s_w[p][n0];
#pragma unroll
    for (int j = 0; j < 4; ++j) {
      unsigned int v = xc[(n0 + j) * 256];
      float x0 = __uint_as_float(v << 16);
      float x1 = __uint_as_float(v & 0xffff0000u);
#pragma unroll
      for (int p = 0; p < PARTC; ++p) {
        u0[p] += wv[p][j] * x0;
        u1[p] += wv[p][j] * x1;
      }
    }
  }
#pragma unroll
  for (int n = 160; n < NTOK; ++n) {
    unsigned int v = xc[n * 256];
    float x0 = __uint_as_float(v << 16);
    float x1 = __uint_as_float(v & 0xffff0000u);
#pragma unroll
    for (int p = 0; p < PARTC; ++p) {
      u0[p] += s_w[p][n] * x0;
      u1[p] += s_w[p][n] * x1;
    }
  }

  // LN: y = u/(l*sqrt(512)); normalize over d
  float y0[PARTC], y1[PARTC], s1[PARTC], s2[PARTC];
#pragma unroll
  for (int p = 0; p < PARTC; ++p) {
    float inv = 1.f / (s_l[p] * SCALING);
    y0[p] = u0[p] * inv;
    y1[p] = u1[p] * inv;
    s1[p] = y0[p] + y1[p];
    s2[p] = y0[p] * y0[p] + y1[p] * y1[p];
  }
#pragma unroll
  for (int off = 32; off > 0; off >>= 1) {
#pragma unroll
    for (int p = 0; p < PARTC; ++p) {
      s1[p] += __shfl_xor(s1[p], off);
      s2[p] += __shfl_xor(s2[p], off);
    }
  }
  if (lane == 0) {
#pragma unroll
    for (int p = 0; p < PARTC; ++p) {
      s_red[w][p] = s1[p];
      s_red[w][PARTC + p] = s2[p];
    }
  }
  __syncthreads();

  const float ga0 = g[2 * tid], ga1 = g[2 * tid + 1];
  const float bb0 = bta[2 * tid], bb1 = bta[2 * tid + 1];
  __hip_bfloat16* orow = outp + (size_t)b * PARTC * DIMC;
#pragma unroll
  for (int p = 0; p < PARTC; ++p) {
    float S = s_red[0][p] + s_red[1][p] + s_red[2][p] + s_red[3][p];
    float Q = s_red[0][PARTC + p] + s_red[1][PARTC + p] + s_red[2][PARTC + p] + s_red[3][PARTC + p];
    float mu = S * (1.f / 512.f);
    float var = Q * (1.f / 512.f) - mu * mu;
    float r = rsqrtf(var + LNEPS);
    __hip_bfloat162 hv;
    hv.x = __float2bfloat16((y0[p] - mu) * r * ga0 + bb0);
    hv.y = __float2bfloat16((y1[p] - mu) * r * ga1 + bb1);
    *(__hip_bfloat162*)(orow + p * DIMC + 2 * tid) = hv;
  }
}

// ---------------------------------------------------------------------------
// MFMA GEMM: C[M][N] = act(A[M][K] @ Bt[N][K]^T + bias)   (unchanged)
// ---------------------------------------------------------------------------
template <int BM, int BN, bool GELU>
__global__ __launch_bounds__(256) void gemm_bt(
    const __hip_bfloat16* __restrict__ A,
    const __hip_bfloat16* __restrict__ Bt,
    const float* __restrict__ bias,
    void* __restrict__ Cv,
    int M, int N, int K)
{
  constexpr int BK = 64;
  constexpr int LDT = BK + 16; // 80 bf16 = 160B row stride
  __shared__ __align__(16) unsigned short Al[BM][LDT];
  __shared__ __align__(16) unsigned short Bl[BN][LDT];

  const int tid = threadIdx.x;
  const int w = tid >> 6, lane = tid & 63;
  const int wr = w >> 1, wc = w & 1;
  const int tm = blockIdx.y * BM, tn = blockIdx.x * BN;
  constexpr int FM = BM / 32, FN = BN / 32;

  f32x4 acc[FM][FN];
#pragma unroll
  for (int m = 0; m < FM; ++m)
#pragma unroll
    for (int n = 0; n < FN; ++n) acc[m][n] = (f32x4){0.f, 0.f, 0.f, 0.f};

  const int srow = tid >> 3;        // 0..31
  const int scol = (tid & 7) * 8;   // element offset in K

  for (int k0 = 0; k0 < K; k0 += BK) {
    __syncthreads();
#pragma unroll
    for (int r = 0; r < BM / 32; ++r) {
      int row = r * 32 + srow;
      *(int4*)(&Al[row][scol]) =
          *(const int4*)(A + (size_t)(tm + row) * K + k0 + scol);
    }
#pragma unroll
    for (int r = 0; r < BN / 32; ++r) {
      int row = r * 32 + srow;
      *(int4*)(&Bl[row][scol]) =
          *(const int4*)(Bt + (size_t)(tn + row) * K + k0 + scol);
    }
    __syncthreads();

#pragma unroll
    for (int kk = 0; kk < 2; ++kk) {
      const int ko = kk * 32 + (lane >> 4) * 8;
      bf16x8 af[FM], bfr[FN];
#pragma unroll
      for (int m = 0; m < FM; ++m)
        af[m] = *(const bf16x8*)(&Al[wr * (BM / 2) + m * 16 + (lane & 15)][ko]);
#pragma unroll
      for (int n = 0; n < FN; ++n)
        bfr[n] = *(const bf16x8*)(&Bl[wc * (BN / 2) + n * 16 + (lane & 15)][ko]);
#pragma unroll
      for (int m = 0; m < FM; ++m)
#pragma unroll
        for (int n = 0; n < FN; ++n)
          acc[m][n] = __builtin_amdgcn_mfma_f32_16x16x32_bf16(
              af[m], bfr[n], acc[m][n], 0, 0, 0);
    }
  }

  // Epilogue: C/D layout col = lane&15, row = (lane>>4)*4 + r  [m89-verified]
  const int cl = lane & 15, rg = (lane >> 4) * 4;
#pragma unroll
  for (int m = 0; m < FM; ++m) {
#pragma unroll
    for (int n = 0; n < FN; ++n) {
      int col = tn + wc * (BN / 2) + n * 16 + cl;
      float bv = bias[col];
#pragma unroll
      for (int r = 0; r < 4; ++r) {
        int row = tm + wr * (BM / 2) + m * 16 + rg + r;
        float v = acc[m][n][r] + bv;
        if (GELU) {
          v = 0.5f * v * (1.f + erff(v * 0.7071067811865476f));
          ((__hip_bfloat16*)Cv)[(size_t)row * N + col] = __float2bfloat16(v);
        } else {
          ((float*)Cv)[(size_t)row * N + col] = v;
        }
      }
    }
  }
}

// ---------------------------------------------------------------------------
extern "C" void kernel_launch(void* const* d_in, const int* in_sizes, int n_in,
                              void* d_out, int out_size, void* d_ws, size_t ws_size,
                              hipStream_t stream)
{
  const float* x   = (const float*)d_in[0];
  const float* pt  = (const float*)d_in[1];
  const float* g   = (const float*)d_in[2];
  const float* bta = (const float*)d_in[3];
  const float* W1  = (const float*)d_in[4];
  const float* b1  = (const float*)d_in[5];
  const float* W2  = (const float*)d_in[6];
  const float* b2  = (const float*)d_in[7];
  float* outp = (float*)d_out;

  char* ws = (char*)d_ws;
  __hip_bfloat16* W1T = (__hip_bfloat16*)(ws);                    // 2048x512  bf16 (2 MB)
  __hip_bfloat16* W2T = (__hip_bfloat16*)(ws + (1u << 21));       // 512x2048  bf16 (2 MB)
  __hip_bfloat16* LNO = (__hip_bfloat16*)(ws + (1u << 22));       // 6144x512  bf16 (6 MB)
  __hip_bfloat16* H   = (__hip_bfloat16*)(ws + 10485760);         // 6144x2048 bf16 (24 MB)
  __hip_bfloat16* XB  = (__hip_bfloat16*)(ws + 35651584);         // 165888x512 bf16 (162 MB)
  float*          LG  = (float*)(ws + 35651584 + 169869312);      // 1024x6x162 f32 (4 MB)

  // K0: W1 (512x2048) -> W1T (2048x512); W2 (2048x512) -> W2T (512x2048)
  transpose_f32_bf16<<<dim3(2048 / 32, 512 / 32), dim3(32, 8), 0, stream>>>(W1, W1T, 512, 2048);
  transpose_f32_bf16<<<dim3(512 / 32, 2048 / 32), dim3(32, 8), 0, stream>>>(W2, W2T, 2048, 512);

  // K1a: logits + bf16 conversion of x
  logits_conv_k<<<2048, 256, 0, stream>>>(x, pt, XB, LG);

  // K1b: softmax + PV + LN -> LNO
  pv_ln_k<<<1024, 256, 0, stream>>>(XB, LG, g, bta, LNO);

  // K2: h = gelu(LNO @ W1 + b1) -> H (bf16)
  gemm_bt<128, 128, true><<<dim3(2048 / 128, 6144 / 128), 256, 0, stream>>>(
      LNO, W1T, b1, (void*)H, 6144, 2048, 512);

  // K3: out = H @ W2 + b2 -> d_out (f32)
  gemm_bt<64, 64, false><<<dim3(512 / 64, 6144 / 64), 256, 0, stream>>>(
      H, W2T, b2, (void*)outp, 6144, 512, 2048);
}